// Round 1
// baseline (108.381 us; speedup 1.0000x reference)
//
#include <hip/hip_runtime.h>

// TripleGrainSeparatePermuter: per-row stable 3-way stream compaction.
// B=512 rows, N=4096 elements/row. 9 outputs of [B, N+1]=[512,4097] int32,
// concatenated flat in d_out in reference return order:
//   0: coarse_content  1: medium_content  2: fine_content
//   3: coarse_position 4: medium_position 5: fine_position
//   6: coarse_segment  7: medium_segment  8: fine_segment
//
// Restructure vs previous version:
//  - segment arrays (pure constant) stored immediately after load issue
//  - PAD regions of content/pos stored right after counts, BEFORE scatter
//  - raw s_barrier + lgkmcnt(0) (LDS-only deps) so stores stay in flight
//    across barriers instead of being drained by __syncthreads' vmcnt(0)
//  - XOR-swizzled s_packed kills the 8-way bank conflict on stride-4 reads
//  - data-region chunks take a predicate-free path; only the boundary chunk
//    per class runs the full elem() predicate logic

constexpr int N_TOK  = 4096;
constexpr int M_OUT  = N_TOK + 1;   // 4097
constexpr int TPB    = 1024;        // 16 waves/block, 2 blocks/CU
constexpr int NWAVES = TPB / 64;
constexpr int EPT    = N_TOK / TPB; // 4 elements per thread (contiguous chunk)

constexpr int CONTENT_PAD = 1024, CONTENT_EOS = 1025;
// per-class position pad/eos: coarse 128/129, medium 256/257, fine 1024/1025
__device__ __constant__ int POS_PAD[3] = {128, 256, 1024};
__device__ __constant__ int POS_EOS[3] = {129, 257, 1025};

// Bank swizzle: XOR bits [4:2] with bits [7:5]. Bijective on [0,4096).
// Read pattern lane t -> addr base+4t: the 8 lanes sharing (t mod 8) span 8
// consecutive values of addr>>5, so the XOR spreads them over 8 distinct
// bank groups -> conflict-free (2 lanes/bank is free per m136).
__device__ __forceinline__ int swz(int a) { return a ^ ((a >> 3) & 0x1C); }

__global__ __launch_bounds__(TPB, 8) void
triple_grain_permute(const int* __restrict__ indices,
                     const int* __restrict__ grain,
                     int* __restrict__ out,
                     int batch) {
    const int b = blockIdx.x;
    const int t = threadIdx.x;
    const int lane = t & 63;
    const int wave = t >> 6;

    const int* idx_row = indices + (size_t)b * N_TOK;
    const int* g_row   = grain   + (size_t)b * N_TOK;

    // packed per-token word: content (bits 0..11, values<=1023) | pos<<12 (<=4095)
    __shared__ int s_packed[N_TOK];
    __shared__ unsigned int s_wave_tot[NWAVES];

    // ---- issue input loads first (hide HBM latency under the stores below) ----
    const int4 gg = reinterpret_cast<const int4*>(g_row)[t];
    const int4 ii = reinterpret_cast<const int4*>(idx_row)[t];

    // ---- output geometry ----
    // Row start (in dwords) = (arr*512 + b)*4097 ≡ b (mod 4); peeling
    // (4 - (b&3)) & 3 leading slots makes the body int4-aligned for all 9 arrays.
    const size_t ARR = (size_t)batch * M_OUT;   // elements per output array
    const int peel = (4 - (b & 3)) & 3;
    const int nch  = (M_OUT - peel) >> 2;       // int4 chunks (<= 1024)
    const int rem  = (M_OUT - peel) & 3;        // tail scalars
    const int s0   = peel + 4 * t;              // my chunk's first slot

    // ---- segment arrays: pure constants, no dependencies -> store NOW ----
#pragma unroll
    for (int c = 0; c < 3; ++c) {
        int* dst_s = out + (size_t)(6 + c) * ARR + (size_t)b * M_OUT;
        if (t < peel) dst_s[t] = c;
        if (t < nch)  *reinterpret_cast<int4*>(dst_s + s0) = make_int4(c, c, c, c);
        if (t < rem)  dst_s[M_OUT - rem + t] = c;
    }

    // ---- unpack loads ----
    int gv[EPT] = {gg.x, gg.y, gg.z, gg.w};
    const int elem0 = t * EPT;
    int pv[EPT] = {ii.x | (elem0 << 12),
                   ii.y | ((elem0 + 1) << 12),
                   ii.z | ((elem0 + 2) << 12),
                   ii.w | ((elem0 + 3) << 12)};

    // ---- per-thread class counts (<=4), packed into 10-bit fields ----
    int c0 = 0, c1 = 0, c2 = 0;
#pragma unroll
    for (int j = 0; j < EPT; ++j) {
        c0 += (gv[j] == 0);
        c1 += (gv[j] == 1);
        c2 += (gv[j] == 2);
    }
    unsigned int packed = (unsigned)c0 | ((unsigned)c1 << 10) | ((unsigned)c2 << 20);

    // ---- wave-64 inclusive scan, 32-bit (covers all 3 classes at once) ----
    unsigned int inc = packed;
#pragma unroll
    for (int off = 1; off < 64; off <<= 1) {
        unsigned int nb = (unsigned int)__shfl_up((int)inc, off, 64);
        if (lane >= off) inc += nb;
    }
    if (lane == 63) s_wave_tot[wave] = inc;

    // LDS-only barrier: do NOT drain vmcnt (segment stores stay in flight)
    asm volatile("s_waitcnt lgkmcnt(0)" ::: "memory");
    __builtin_amdgcn_s_barrier();
    __builtin_amdgcn_sched_barrier(0);

    // ---- cross-wave combine (per-class, widened to 32-bit here) ----
    int wp0 = 0, wp1 = 0, wp2 = 0, tot0 = 0, tot1 = 0, tot2 = 0;
#pragma unroll
    for (int w = 0; w < NWAVES; ++w) {
        const unsigned int v = s_wave_tot[w];
        const int f0 = v & 1023, f1 = (v >> 10) & 1023, f2 = (v >> 20) & 1023;
        if (w < wave) { wp0 += f0; wp1 += f1; wp2 += f2; }
        tot0 += f0; tot1 += f1; tot2 += f2;
    }
    const unsigned int exv = inc - packed;   // per-field exclusive (no borrow)
    const int o0 = wp0 + (int)(exv & 1023);
    const int o1 = wp1 + (int)((exv >> 10) & 1023);
    const int o2 = wp2 + (int)((exv >> 20) & 1023);
    const int cnt0 = tot0, cnt1 = tot1, cnt2 = tot2;
    const int base0 = 0, base1 = cnt0, base2 = cnt0 + cnt1;

    const int bases[3] = {base0, base1, base2};
    const int cnts[3]  = {cnt0, cnt1, cnt2};

    // ---- PAD regions of content/pos depend only on cnt: store BEFORE the
    //      scatter so these ~2/3 of the store traffic drain under compute ----
#pragma unroll
    for (int c = 0; c < 3; ++c) {
        if (t < nch && s0 > cnts[c]) {   // entire chunk strictly past EOS
            int* dst_c = out + (size_t)c       * ARR + (size_t)b * M_OUT;
            int* dst_p = out + (size_t)(3 + c) * ARR + (size_t)b * M_OUT;
            *reinterpret_cast<int4*>(dst_c + s0) =
                make_int4(CONTENT_PAD, CONTENT_PAD, CONTENT_PAD, CONTENT_PAD);
            const int pp = POS_PAD[c];
            *reinterpret_cast<int4*>(dst_p + s0) = make_int4(pp, pp, pp, pp);
        }
    }

    // ---- scatter my chunk into (swizzled) LDS ----
    int d0 = base0 + o0, d1 = base1 + o1, d2 = base2 + o2;
#pragma unroll
    for (int j = 0; j < EPT; ++j) {
        const int cl = gv[j];
        const int dst = (cl == 0) ? d0 : ((cl == 1) ? d1 : d2);
        s_packed[swz(dst)] = pv[j];
        d0 += (cl == 0);
        d1 += (cl == 1);
        d2 += (cl == 2);
    }

    // LDS-only barrier again: PAD stores keep flying
    asm volatile("s_waitcnt lgkmcnt(0)" ::: "memory");
    __builtin_amdgcn_s_barrier();
    __builtin_amdgcn_sched_barrier(0);

    // ---- data-region write-out ----
#pragma unroll
    for (int c = 0; c < 3; ++c) {
        int* dst_c = out + (size_t)c       * ARR + (size_t)b * M_OUT;
        int* dst_p = out + (size_t)(3 + c) * ARR + (size_t)b * M_OUT;
        const int cnt = cnts[c];
        const int base = bases[c];
        const int peos = POS_EOS[c], ppad = POS_PAD[c];

        auto elem = [&](int slot, int& vc, int& vp) {
            int a = base + slot;
            a = (a > N_TOK - 1) ? (N_TOK - 1) : a;   // pad lanes read junk, discarded
            const int pk = s_packed[swz(a)];
            vc = (slot < cnt) ? (pk & 0xFFF) : ((slot == cnt) ? CONTENT_EOS : CONTENT_PAD);
            vp = (slot < cnt) ? (pk >> 12)   : ((slot == cnt) ? peos : ppad);
        };

        if (t < peel) {                      // leading scalars to alignment
            int vc, vp;
            elem(t, vc, vp);
            dst_c[t] = vc; dst_p[t] = vp;
        }
        if (t < nch) {
            if (s0 + 3 < cnt) {
                // pure data chunk: predicate-free, conflict-free swizzled reads
                const int a = base + s0;
                const int p0 = s_packed[swz(a)];
                const int p1 = s_packed[swz(a + 1)];
                const int p2 = s_packed[swz(a + 2)];
                const int p3 = s_packed[swz(a + 3)];
                *reinterpret_cast<int4*>(dst_c + s0) =
                    make_int4(p0 & 0xFFF, p1 & 0xFFF, p2 & 0xFFF, p3 & 0xFFF);
                *reinterpret_cast<int4*>(dst_p + s0) =
                    make_int4(p0 >> 12, p1 >> 12, p2 >> 12, p3 >> 12);
            } else if (s0 <= cnt) {
                // boundary chunk (contains EOS): full predicate path
                int4 vc4, vp4;
                elem(s0 + 0, vc4.x, vp4.x);
                elem(s0 + 1, vc4.y, vp4.y);
                elem(s0 + 2, vc4.z, vp4.z);
                elem(s0 + 3, vc4.w, vp4.w);
                *reinterpret_cast<int4*>(dst_c + s0) = vc4;
                *reinterpret_cast<int4*>(dst_p + s0) = vp4;
            }
            // s0 > cnt: already stored in the PAD phase
        }
        if (t < rem) {                       // tail scalars
            const int slot = M_OUT - rem + t;
            int vc, vp;
            elem(slot, vc, vp);
            dst_c[slot] = vc; dst_p[slot] = vp;
        }
    }
}

extern "C" void kernel_launch(void* const* d_in, const int* in_sizes, int n_in,
                              void* d_out, int out_size, void* d_ws, size_t ws_size,
                              hipStream_t stream) {
    const int* indices = (const int*)d_in[0];
    const int* grain   = (const int*)d_in[1];
    int* out = (int*)d_out;

    const int batch = in_sizes[0] / N_TOK;  // 512
    triple_grain_permute<<<batch, TPB, 0, stream>>>(indices, grain, out, batch);
}

// Round 2
// 97.412 us; speedup vs baseline: 1.1126x; 1.1126x over previous
//
#include <hip/hip_runtime.h>

// TripleGrainSeparatePermuter: per-row stable 3-way stream compaction.
// B=512 rows, N=4096 elements/row. 9 outputs of [B, N+1]=[512,4097] int32,
// concatenated flat in d_out in reference return order:
//   0: coarse_content  1: medium_content  2: fine_content
//   3: coarse_position 4: medium_position 5: fine_position
//   6: coarse_segment  7: medium_segment  8: fine_segment
//
// Round-0 structure (single write phase, __syncthreads) + three isolated deltas:
//  1. s_packed XOR-swizzle: stride-4 write-phase reads were 8-way bank
//     conflicts (lanes sharing t%8 hit one bank); swizzle spreads them.
//  2. PAD-chunk shortcut: chunks entirely past EOS store constants directly
//     (no LDS read, no predicates) -- ~2/3 of all chunks.
//  3. Segment arrays (pure constant, 33% of store traffic) offloaded to
//     interleaved sibling blocks (odd blockIdx.x) so they stream at
//     fill-rate BW concurrently with the compaction blocks' compute phases.

constexpr int N_TOK  = 4096;
constexpr int M_OUT  = N_TOK + 1;   // 4097
constexpr int TPB    = 1024;        // 16 waves/block, 2 blocks/CU
constexpr int NWAVES = TPB / 64;
constexpr int EPT    = N_TOK / TPB; // 4 elements per thread (contiguous chunk)

constexpr int CONTENT_PAD = 1024, CONTENT_EOS = 1025;
// per-class position pad/eos: coarse 128/129, medium 256/257, fine 1024/1025
__device__ __constant__ int POS_PAD[3] = {128, 256, 1024};
__device__ __constant__ int POS_EOS[3] = {129, 257, 1025};

// Bank swizzle: XOR bits [4:2] with bits [7:5]. Bijective on [0,4096).
// Write-phase read lane t -> addrs base+4t+j: the 8 lanes sharing (t mod 8)
// span 8 consecutive values of addr bits [7:5], so the XOR gives them 8
// distinct bank groups -> conflict-free (2 lanes/bank is free per m136).
__device__ __forceinline__ int swz(int a) { return a ^ ((a >> 3) & 0x1C); }

__global__ __launch_bounds__(TPB, 8) void
triple_grain_permute(const int* __restrict__ indices,
                     const int* __restrict__ grain,
                     int* __restrict__ out,
                     int batch) {
    // interleaved roles: even blocks = compaction row, odd = segment fill row.
    const int b    = blockIdx.x >> 1;
    const int role = blockIdx.x & 1;
    const int t = threadIdx.x;
    const int lane = t & 63;
    const int wave = t >> 6;

    // ---- output geometry ----
    // Row start (in dwords) = (arr*512 + b)*4097 ≡ b (mod 4); peeling
    // (4 - (b&3)) & 3 leading slots makes the body int4-aligned for all arrays.
    const size_t ARR = (size_t)batch * M_OUT;   // elements per output array
    const int peel = (4 - (b & 3)) & 3;
    const int nch  = (M_OUT - peel) >> 2;       // int4 chunks (<= 1024)
    const int rem  = (M_OUT - peel) & 3;        // tail scalars
    const int s0   = peel + 4 * t;              // my chunk's first slot

    if (role == 1) {
        // ---- segment-fill block: 3 rows of pure constants, no LDS/barriers ----
#pragma unroll
        for (int c = 0; c < 3; ++c) {
            int* dst_s = out + (size_t)(6 + c) * ARR + (size_t)b * M_OUT;
            if (t < peel) dst_s[t] = c;
            if (t < nch)  *reinterpret_cast<int4*>(dst_s + s0) = make_int4(c, c, c, c);
            if (t < rem)  dst_s[M_OUT - rem + t] = c;
        }
        return;
    }

    const int* idx_row = indices + (size_t)b * N_TOK;
    const int* g_row   = grain   + (size_t)b * N_TOK;

    // packed per-token word: content (bits 0..11, values<=1023) | pos<<12 (<=4095)
    __shared__ int s_packed[N_TOK];
    __shared__ unsigned int s_wave_tot[NWAVES];

    // ---- load my contiguous 4-element chunk (int4, 16B-aligned) ----
    int4 gg = reinterpret_cast<const int4*>(g_row)[t];
    int4 ii = reinterpret_cast<const int4*>(idx_row)[t];
    int gv[EPT] = {gg.x, gg.y, gg.z, gg.w};
    const int elem0 = t * EPT;
    int pv[EPT] = {ii.x | (elem0 << 12),
                   ii.y | ((elem0 + 1) << 12),
                   ii.z | ((elem0 + 2) << 12),
                   ii.w | ((elem0 + 3) << 12)};

    // ---- per-thread class counts (<=4), packed into 10-bit fields.
    // Wave-inclusive field max = 64*4 = 256 < 1024: no cross-field carry in u32.
    int c0 = 0, c1 = 0, c2 = 0;
#pragma unroll
    for (int j = 0; j < EPT; ++j) {
        c0 += (gv[j] == 0);
        c1 += (gv[j] == 1);
        c2 += (gv[j] == 2);
    }
    unsigned int packed = (unsigned)c0 | ((unsigned)c1 << 10) | ((unsigned)c2 << 20);

    // ---- wave-64 inclusive scan, 32-bit (covers all 3 classes at once) ----
    unsigned int inc = packed;
#pragma unroll
    for (int off = 1; off < 64; off <<= 1) {
        unsigned int nb = (unsigned int)__shfl_up((int)inc, off, 64);
        if (lane >= off) inc += nb;
    }
    if (lane == 63) s_wave_tot[wave] = inc;
    __syncthreads();

    // ---- cross-wave combine (per-class, 32-bit fields widened here) ----
    int wp0 = 0, wp1 = 0, wp2 = 0, tot0 = 0, tot1 = 0, tot2 = 0;
#pragma unroll
    for (int w = 0; w < NWAVES; ++w) {
        const unsigned int v = s_wave_tot[w];
        const int f0 = v & 1023, f1 = (v >> 10) & 1023, f2 = (v >> 20) & 1023;
        if (w < wave) { wp0 += f0; wp1 += f1; wp2 += f2; }
        tot0 += f0; tot1 += f1; tot2 += f2;
    }
    const unsigned int exv = inc - packed;   // per-field exclusive (no borrow)
    const int o0 = wp0 + (int)(exv & 1023);
    const int o1 = wp1 + (int)((exv >> 10) & 1023);
    const int o2 = wp2 + (int)((exv >> 20) & 1023);
    const int cnt0 = tot0, cnt1 = tot1, cnt2 = tot2;

    // compacted class segments laid back-to-back in LDS
    const int base0 = 0, base1 = cnt0, base2 = cnt0 + cnt1;

    // ---- scatter my chunk into (swizzled) LDS (stable: contiguous chunk) ----
    int d0 = base0 + o0, d1 = base1 + o1, d2 = base2 + o2;
#pragma unroll
    for (int j = 0; j < EPT; ++j) {
        const int c = gv[j];
        const int dst = (c == 0) ? d0 : ((c == 1) ? d1 : d2);
        s_packed[swz(dst)] = pv[j];
        d0 += (c == 0);
        d1 += (c == 1);
        d2 += (c == 2);
    }
    __syncthreads();

    // ---- vectorized coalesced write-out (content + position; segments are
    //      handled by the sibling fill blocks) ----
    const int bases[3] = {base0, base1, base2};
    const int cnts[3]  = {cnt0, cnt1, cnt2};

#pragma unroll
    for (int c = 0; c < 3; ++c) {
        int* dst_c = out + (size_t)c       * ARR + (size_t)b * M_OUT;
        int* dst_p = out + (size_t)(3 + c) * ARR + (size_t)b * M_OUT;
        const int cnt = cnts[c];
        const int base = bases[c];
        const int peos = POS_EOS[c], ppad = POS_PAD[c];

        auto elem = [&](int slot, int& vc, int& vp) {
            int a = base + slot;
            a = (a > N_TOK - 1) ? (N_TOK - 1) : a;   // pad lanes read junk, discarded
            const int pk = s_packed[swz(a)];
            vc = (slot < cnt) ? (pk & 0xFFF) : ((slot == cnt) ? CONTENT_EOS : CONTENT_PAD);
            vp = (slot < cnt) ? (pk >> 12)   : ((slot == cnt) ? peos : ppad);
        };

        if (t < peel) {                      // leading scalars to alignment
            int vc, vp;
            elem(t, vc, vp);
            dst_c[t] = vc; dst_p[t] = vp;
        }
        if (t < nch) {                       // aligned int4 body, one chunk/thread
            if (s0 + 3 < cnt) {
                // pure data chunk: no predicates, conflict-free swizzled reads
                const int a = base + s0;
                const int p0 = s_packed[swz(a)];
                const int p1 = s_packed[swz(a + 1)];
                const int p2 = s_packed[swz(a + 2)];
                const int p3 = s_packed[swz(a + 3)];
                *reinterpret_cast<int4*>(dst_c + s0) =
                    make_int4(p0 & 0xFFF, p1 & 0xFFF, p2 & 0xFFF, p3 & 0xFFF);
                *reinterpret_cast<int4*>(dst_p + s0) =
                    make_int4(p0 >> 12, p1 >> 12, p2 >> 12, p3 >> 12);
            } else if (s0 > cnt) {
                // pure PAD chunk: constants only, no LDS traffic
                *reinterpret_cast<int4*>(dst_c + s0) =
                    make_int4(CONTENT_PAD, CONTENT_PAD, CONTENT_PAD, CONTENT_PAD);
                *reinterpret_cast<int4*>(dst_p + s0) =
                    make_int4(ppad, ppad, ppad, ppad);
            } else {
                // boundary chunk (contains EOS): full predicate path
                int4 vc4, vp4;
                elem(s0 + 0, vc4.x, vp4.x);
                elem(s0 + 1, vc4.y, vp4.y);
                elem(s0 + 2, vc4.z, vp4.z);
                elem(s0 + 3, vc4.w, vp4.w);
                *reinterpret_cast<int4*>(dst_c + s0) = vc4;
                *reinterpret_cast<int4*>(dst_p + s0) = vp4;
            }
        }
        if (t < rem) {                       // tail scalars
            const int slot = M_OUT - rem + t;
            int vc, vp;
            elem(slot, vc, vp);
            dst_c[slot] = vc; dst_p[slot] = vp;
        }
    }
}

extern "C" void kernel_launch(void* const* d_in, const int* in_sizes, int n_in,
                              void* d_out, int out_size, void* d_ws, size_t ws_size,
                              hipStream_t stream) {
    const int* indices = (const int*)d_in[0];
    const int* grain   = (const int*)d_in[1];
    int* out = (int*)d_out;

    const int batch = in_sizes[0] / N_TOK;  // 512
    triple_grain_permute<<<2 * batch, TPB, 0, stream>>>(indices, grain, out, batch);
}

// Round 3
// 90.745 us; speedup vs baseline: 1.1943x; 1.0735x over previous
//
#include <hip/hip_runtime.h>

// TripleGrainSeparatePermuter: per-row stable 3-way stream compaction.
// B=512 rows, N=4096 elements/row. 9 outputs of [B, N+1]=[512,4097] int32,
// concatenated flat in d_out in reference return order:
//   0: coarse_content  1: medium_content  2: fine_content
//   3: coarse_position 4: medium_position 5: fine_position
//   6: coarse_segment  7: medium_segment  8: fine_segment
//
// Round-0 structure and grid exactly (512 blocks, __syncthreads, single
// unified write loop), plus three write-phase-only deltas:
//  1. Segment arrays (pure constants, 33% of store traffic) stored at the
//     TOP of the kernel: the stores issue before the scan and drain from
//     the store queue during scan/combine/scatter instead of serializing
//     into the write-phase tail. (No extra blocks -- round 1's offload to
//     sibling blocks cost co-residency and regressed.)
//  2. s_packed XOR-swizzle: the stride-4 write-phase read pattern was an
//     8-way bank conflict (lanes sharing t%8 -> same bank); swizzle spreads
//     them across 8 bank groups (2 lanes/bank is free, m136).
//  3. PAD-chunk shortcut: chunks entirely past EOS (~2/3 of all chunks at
//     cnt~N/3) store constants directly -- no LDS reads, no predicates.

constexpr int N_TOK  = 4096;
constexpr int M_OUT  = N_TOK + 1;   // 4097
constexpr int TPB    = 1024;        // 16 waves/block, 2 blocks/CU
constexpr int NWAVES = TPB / 64;
constexpr int EPT    = N_TOK / TPB; // 4 elements per thread (contiguous chunk)

constexpr int CONTENT_PAD = 1024, CONTENT_EOS = 1025;
// per-class position pad/eos: coarse 128/129, medium 256/257, fine 1024/1025
__device__ __constant__ int POS_PAD[3] = {128, 256, 1024};
__device__ __constant__ int POS_EOS[3] = {129, 257, 1025};

// Bank swizzle: XOR bits [4:2] with bits [7:5]. Involution, bijective on
// [0,4096), permutes within each aligned 32-dword block (so scatter-write
// locality is preserved). Write-phase read lane t -> addrs base+4t+j: the 8
// lanes sharing (t mod 8) span 8 consecutive values of addr bits [7:5], so
// the XOR gives them 8 distinct bank groups -> conflict-free.
__device__ __forceinline__ int swz(int a) { return a ^ ((a >> 3) & 0x1C); }

__global__ __launch_bounds__(TPB, 8) void
triple_grain_permute(const int* __restrict__ indices,
                     const int* __restrict__ grain,
                     int* __restrict__ out,
                     int batch) {
    const int b = blockIdx.x;
    const int t = threadIdx.x;
    const int lane = t & 63;
    const int wave = t >> 6;

    const int* idx_row = indices + (size_t)b * N_TOK;
    const int* g_row   = grain   + (size_t)b * N_TOK;

    // packed per-token word: content (bits 0..11, values<=1023) | pos<<12 (<=4095)
    __shared__ int s_packed[N_TOK];
    __shared__ unsigned int s_wave_tot[NWAVES];

    // ---- issue input loads first ----
    const int4 gg = reinterpret_cast<const int4*>(g_row)[t];
    const int4 ii = reinterpret_cast<const int4*>(idx_row)[t];

    // ---- output geometry ----
    // Row start (in dwords) = (arr*512 + b)*4097 ≡ b (mod 4); peeling
    // (4 - (b&3)) & 3 leading slots makes the body int4-aligned for all arrays.
    const size_t ARR = (size_t)batch * M_OUT;   // elements per output array
    const int peel = (4 - (b & 3)) & 3;
    const int nch  = (M_OUT - peel) >> 2;       // int4 chunks (<= 1024)
    const int rem  = (M_OUT - peel) & 3;        // tail scalars
    const int s0   = peel + 4 * t;              // my chunk's first slot

    // ---- segment arrays: pure constants, no dependencies -> store NOW so
    //      they drain during the scan/combine/scatter phases ----
#pragma unroll
    for (int c = 0; c < 3; ++c) {
        int* dst_s = out + (size_t)(6 + c) * ARR + (size_t)b * M_OUT;
        if (t < peel) dst_s[t] = c;
        if (t < nch)  *reinterpret_cast<int4*>(dst_s + s0) = make_int4(c, c, c, c);
        if (t < rem)  dst_s[M_OUT - rem + t] = c;
    }

    // ---- unpack loads ----
    int gv[EPT] = {gg.x, gg.y, gg.z, gg.w};
    const int elem0 = t * EPT;
    int pv[EPT] = {ii.x | (elem0 << 12),
                   ii.y | ((elem0 + 1) << 12),
                   ii.z | ((elem0 + 2) << 12),
                   ii.w | ((elem0 + 3) << 12)};

    // ---- per-thread class counts (<=4), packed into 10-bit fields.
    // Wave-inclusive field max = 64*4 = 256 < 1024: no cross-field carry in u32.
    int c0 = 0, c1 = 0, c2 = 0;
#pragma unroll
    for (int j = 0; j < EPT; ++j) {
        c0 += (gv[j] == 0);
        c1 += (gv[j] == 1);
        c2 += (gv[j] == 2);
    }
    unsigned int packed = (unsigned)c0 | ((unsigned)c1 << 10) | ((unsigned)c2 << 20);

    // ---- wave-64 inclusive scan, 32-bit (covers all 3 classes at once) ----
    unsigned int inc = packed;
#pragma unroll
    for (int off = 1; off < 64; off <<= 1) {
        unsigned int nb = (unsigned int)__shfl_up((int)inc, off, 64);
        if (lane >= off) inc += nb;
    }
    if (lane == 63) s_wave_tot[wave] = inc;
    __syncthreads();

    // ---- cross-wave combine (per-class, 32-bit fields widened here) ----
    int wp0 = 0, wp1 = 0, wp2 = 0, tot0 = 0, tot1 = 0, tot2 = 0;
#pragma unroll
    for (int w = 0; w < NWAVES; ++w) {
        const unsigned int v = s_wave_tot[w];
        const int f0 = v & 1023, f1 = (v >> 10) & 1023, f2 = (v >> 20) & 1023;
        if (w < wave) { wp0 += f0; wp1 += f1; wp2 += f2; }
        tot0 += f0; tot1 += f1; tot2 += f2;
    }
    const unsigned int exv = inc - packed;   // per-field exclusive (no borrow)
    const int o0 = wp0 + (int)(exv & 1023);
    const int o1 = wp1 + (int)((exv >> 10) & 1023);
    const int o2 = wp2 + (int)((exv >> 20) & 1023);
    const int cnt0 = tot0, cnt1 = tot1, cnt2 = tot2;

    // compacted class segments laid back-to-back in LDS
    const int base0 = 0, base1 = cnt0, base2 = cnt0 + cnt1;

    // ---- scatter my chunk into (swizzled) LDS (stable: contiguous chunk) ----
    int d0 = base0 + o0, d1 = base1 + o1, d2 = base2 + o2;
#pragma unroll
    for (int j = 0; j < EPT; ++j) {
        const int c = gv[j];
        const int dst = (c == 0) ? d0 : ((c == 1) ? d1 : d2);
        s_packed[swz(dst)] = pv[j];
        d0 += (c == 0);
        d1 += (c == 1);
        d2 += (c == 2);
    }
    __syncthreads();

    // ---- vectorized coalesced write-out (content + position) ----
    const int bases[3] = {base0, base1, base2};
    const int cnts[3]  = {cnt0, cnt1, cnt2};

#pragma unroll
    for (int c = 0; c < 3; ++c) {
        int* dst_c = out + (size_t)c       * ARR + (size_t)b * M_OUT;
        int* dst_p = out + (size_t)(3 + c) * ARR + (size_t)b * M_OUT;
        const int cnt = cnts[c];
        const int base = bases[c];
        const int peos = POS_EOS[c], ppad = POS_PAD[c];

        auto elem = [&](int slot, int& vc, int& vp) {
            int a = base + slot;
            a = (a > N_TOK - 1) ? (N_TOK - 1) : a;   // pad lanes read junk, discarded
            const int pk = s_packed[swz(a)];
            vc = (slot < cnt) ? (pk & 0xFFF) : ((slot == cnt) ? CONTENT_EOS : CONTENT_PAD);
            vp = (slot < cnt) ? (pk >> 12)   : ((slot == cnt) ? peos : ppad);
        };

        if (t < peel) {                      // leading scalars to alignment
            int vc, vp;
            elem(t, vc, vp);
            dst_c[t] = vc; dst_p[t] = vp;
        }
        if (t < nch) {                       // aligned int4 body, one chunk/thread
            if (s0 + 3 < cnt) {
                // pure data chunk: no predicates, conflict-free swizzled reads
                const int a = base + s0;
                const int p0 = s_packed[swz(a)];
                const int p1 = s_packed[swz(a + 1)];
                const int p2 = s_packed[swz(a + 2)];
                const int p3 = s_packed[swz(a + 3)];
                *reinterpret_cast<int4*>(dst_c + s0) =
                    make_int4(p0 & 0xFFF, p1 & 0xFFF, p2 & 0xFFF, p3 & 0xFFF);
                *reinterpret_cast<int4*>(dst_p + s0) =
                    make_int4(p0 >> 12, p1 >> 12, p2 >> 12, p3 >> 12);
            } else if (s0 > cnt) {
                // pure PAD chunk: constants only, no LDS traffic
                *reinterpret_cast<int4*>(dst_c + s0) =
                    make_int4(CONTENT_PAD, CONTENT_PAD, CONTENT_PAD, CONTENT_PAD);
                *reinterpret_cast<int4*>(dst_p + s0) =
                    make_int4(ppad, ppad, ppad, ppad);
            } else {
                // boundary chunk (contains EOS): full predicate path
                int4 vc4, vp4;
                elem(s0 + 0, vc4.x, vp4.x);
                elem(s0 + 1, vc4.y, vp4.y);
                elem(s0 + 2, vc4.z, vp4.z);
                elem(s0 + 3, vc4.w, vp4.w);
                *reinterpret_cast<int4*>(dst_c + s0) = vc4;
                *reinterpret_cast<int4*>(dst_p + s0) = vp4;
            }
        }
        if (t < rem) {                       // tail scalars
            const int slot = M_OUT - rem + t;
            int vc, vp;
            elem(slot, vc, vp);
            dst_c[slot] = vc; dst_p[slot] = vp;
        }
    }
}

extern "C" void kernel_launch(void* const* d_in, const int* in_sizes, int n_in,
                              void* d_out, int out_size, void* d_ws, size_t ws_size,
                              hipStream_t stream) {
    const int* indices = (const int*)d_in[0];
    const int* grain   = (const int*)d_in[1];
    int* out = (int*)d_out;

    const int batch = in_sizes[0] / N_TOK;  // 512
    triple_grain_permute<<<batch, TPB, 0, stream>>>(indices, grain, out, batch);
}

// Round 4
// 90.625 us; speedup vs baseline: 1.1959x; 1.0013x over previous
//
#include <hip/hip_runtime.h>

// TripleGrainSeparatePermuter: per-row stable 3-way stream compaction.
// B=512 rows, N=4096 elements/row. 9 outputs of [B, N+1]=[512,4097] int32,
// concatenated flat in d_out in reference return order:
//   0: coarse_content  1: medium_content  2: fine_content
//   3: coarse_position 4: medium_position 5: fine_position
//   6: coarse_segment  7: medium_segment  8: fine_segment
//
// ROUND 4 DELTA (single, isolated): __launch_bounds__(1024, 8) -> (1024, 4).
// The old bound demanded 8 waves/EU, capping the allocator at 64 VGPR/wave.
// This kernel's epilogue (two int4 input loads, unpacked gv/pv, 9 int4 store
// values + 9 per-lane 64-bit addresses) almost certainly spilled to scratch
// under that cap -- invisible extra HBM traffic that would explain why the
// measured ~43us kernel ignores every instruction-level edit (rounds 1-3 all
// neutral) while per-instruction arithmetic predicts ~15-20us.
// (1024,4) allows 128 VGPR. Asymmetric risk: if no spills existed, codegen
// stays <=64 VGPR and hardware occupancy is unchanged (occupancy follows
// actual usage, not the annotation).
//
// Retained from round 3 (all measured-neutral but harmless):
//  - segment arrays stored at kernel top
//  - s_packed XOR-swizzle (conflict-free stride-4 write-phase reads)
//  - PAD-chunk constant shortcut

constexpr int N_TOK  = 4096;
constexpr int M_OUT  = N_TOK + 1;   // 4097
constexpr int TPB    = 1024;        // 16 waves/block
constexpr int NWAVES = TPB / 64;
constexpr int EPT    = N_TOK / TPB; // 4 elements per thread (contiguous chunk)

constexpr int CONTENT_PAD = 1024, CONTENT_EOS = 1025;
// per-class position pad/eos: coarse 128/129, medium 256/257, fine 1024/1025
__device__ __constant__ int POS_PAD[3] = {128, 256, 1024};
__device__ __constant__ int POS_EOS[3] = {129, 257, 1025};

// Bank swizzle: XOR bits [4:2] with bits [7:5]. Involution, bijective on
// [0,4096), permutes within each aligned 32-dword block (so scatter-write
// locality is preserved). Write-phase read lane t -> addrs base+4t+j: the 8
// lanes sharing (t mod 8) span 8 consecutive values of addr bits [7:5], so
// the XOR gives them 8 distinct bank groups -> conflict-free.
__device__ __forceinline__ int swz(int a) { return a ^ ((a >> 3) & 0x1C); }

__global__ __launch_bounds__(TPB, 4) void
triple_grain_permute(const int* __restrict__ indices,
                     const int* __restrict__ grain,
                     int* __restrict__ out,
                     int batch) {
    const int b = blockIdx.x;
    const int t = threadIdx.x;
    const int lane = t & 63;
    const int wave = t >> 6;

    const int* idx_row = indices + (size_t)b * N_TOK;
    const int* g_row   = grain   + (size_t)b * N_TOK;

    // packed per-token word: content (bits 0..11, values<=1023) | pos<<12 (<=4095)
    __shared__ int s_packed[N_TOK];
    __shared__ unsigned int s_wave_tot[NWAVES];

    // ---- issue input loads first ----
    const int4 gg = reinterpret_cast<const int4*>(g_row)[t];
    const int4 ii = reinterpret_cast<const int4*>(idx_row)[t];

    // ---- output geometry ----
    // Row start (in dwords) = (arr*512 + b)*4097 ≡ b (mod 4); peeling
    // (4 - (b&3)) & 3 leading slots makes the body int4-aligned for all arrays.
    const size_t ARR = (size_t)batch * M_OUT;   // elements per output array
    const int peel = (4 - (b & 3)) & 3;
    const int nch  = (M_OUT - peel) >> 2;       // int4 chunks (<= 1024)
    const int rem  = (M_OUT - peel) & 3;        // tail scalars
    const int s0   = peel + 4 * t;              // my chunk's first slot

    // ---- segment arrays: pure constants, no dependencies -> store NOW so
    //      they drain during the scan/combine/scatter phases ----
#pragma unroll
    for (int c = 0; c < 3; ++c) {
        int* dst_s = out + (size_t)(6 + c) * ARR + (size_t)b * M_OUT;
        if (t < peel) dst_s[t] = c;
        if (t < nch)  *reinterpret_cast<int4*>(dst_s + s0) = make_int4(c, c, c, c);
        if (t < rem)  dst_s[M_OUT - rem + t] = c;
    }

    // ---- unpack loads ----
    int gv[EPT] = {gg.x, gg.y, gg.z, gg.w};
    const int elem0 = t * EPT;
    int pv[EPT] = {ii.x | (elem0 << 12),
                   ii.y | ((elem0 + 1) << 12),
                   ii.z | ((elem0 + 2) << 12),
                   ii.w | ((elem0 + 3) << 12)};

    // ---- per-thread class counts (<=4), packed into 10-bit fields.
    // Wave-inclusive field max = 64*4 = 256 < 1024: no cross-field carry in u32.
    int c0 = 0, c1 = 0, c2 = 0;
#pragma unroll
    for (int j = 0; j < EPT; ++j) {
        c0 += (gv[j] == 0);
        c1 += (gv[j] == 1);
        c2 += (gv[j] == 2);
    }
    unsigned int packed = (unsigned)c0 | ((unsigned)c1 << 10) | ((unsigned)c2 << 20);

    // ---- wave-64 inclusive scan, 32-bit (covers all 3 classes at once) ----
    unsigned int inc = packed;
#pragma unroll
    for (int off = 1; off < 64; off <<= 1) {
        unsigned int nb = (unsigned int)__shfl_up((int)inc, off, 64);
        if (lane >= off) inc += nb;
    }
    if (lane == 63) s_wave_tot[wave] = inc;
    __syncthreads();

    // ---- cross-wave combine (per-class, 32-bit fields widened here) ----
    int wp0 = 0, wp1 = 0, wp2 = 0, tot0 = 0, tot1 = 0, tot2 = 0;
#pragma unroll
    for (int w = 0; w < NWAVES; ++w) {
        const unsigned int v = s_wave_tot[w];
        const int f0 = v & 1023, f1 = (v >> 10) & 1023, f2 = (v >> 20) & 1023;
        if (w < wave) { wp0 += f0; wp1 += f1; wp2 += f2; }
        tot0 += f0; tot1 += f1; tot2 += f2;
    }
    const unsigned int exv = inc - packed;   // per-field exclusive (no borrow)
    const int o0 = wp0 + (int)(exv & 1023);
    const int o1 = wp1 + (int)((exv >> 10) & 1023);
    const int o2 = wp2 + (int)((exv >> 20) & 1023);
    const int cnt0 = tot0, cnt1 = tot1, cnt2 = tot2;

    // compacted class segments laid back-to-back in LDS
    const int base0 = 0, base1 = cnt0, base2 = cnt0 + cnt1;

    // ---- scatter my chunk into (swizzled) LDS (stable: contiguous chunk) ----
    int d0 = base0 + o0, d1 = base1 + o1, d2 = base2 + o2;
#pragma unroll
    for (int j = 0; j < EPT; ++j) {
        const int c = gv[j];
        const int dst = (c == 0) ? d0 : ((c == 1) ? d1 : d2);
        s_packed[swz(dst)] = pv[j];
        d0 += (c == 0);
        d1 += (c == 1);
        d2 += (c == 2);
    }
    __syncthreads();

    // ---- vectorized coalesced write-out (content + position) ----
    const int bases[3] = {base0, base1, base2};
    const int cnts[3]  = {cnt0, cnt1, cnt2};

#pragma unroll
    for (int c = 0; c < 3; ++c) {
        int* dst_c = out + (size_t)c       * ARR + (size_t)b * M_OUT;
        int* dst_p = out + (size_t)(3 + c) * ARR + (size_t)b * M_OUT;
        const int cnt = cnts[c];
        const int base = bases[c];
        const int peos = POS_EOS[c], ppad = POS_PAD[c];

        auto elem = [&](int slot, int& vc, int& vp) {
            int a = base + slot;
            a = (a > N_TOK - 1) ? (N_TOK - 1) : a;   // pad lanes read junk, discarded
            const int pk = s_packed[swz(a)];
            vc = (slot < cnt) ? (pk & 0xFFF) : ((slot == cnt) ? CONTENT_EOS : CONTENT_PAD);
            vp = (slot < cnt) ? (pk >> 12)   : ((slot == cnt) ? peos : ppad);
        };

        if (t < peel) {                      // leading scalars to alignment
            int vc, vp;
            elem(t, vc, vp);
            dst_c[t] = vc; dst_p[t] = vp;
        }
        if (t < nch) {                       // aligned int4 body, one chunk/thread
            if (s0 + 3 < cnt) {
                // pure data chunk: no predicates, conflict-free swizzled reads
                const int a = base + s0;
                const int p0 = s_packed[swz(a)];
                const int p1 = s_packed[swz(a + 1)];
                const int p2 = s_packed[swz(a + 2)];
                const int p3 = s_packed[swz(a + 3)];
                *reinterpret_cast<int4*>(dst_c + s0) =
                    make_int4(p0 & 0xFFF, p1 & 0xFFF, p2 & 0xFFF, p3 & 0xFFF);
                *reinterpret_cast<int4*>(dst_p + s0) =
                    make_int4(p0 >> 12, p1 >> 12, p2 >> 12, p3 >> 12);
            } else if (s0 > cnt) {
                // pure PAD chunk: constants only, no LDS traffic
                *reinterpret_cast<int4*>(dst_c + s0) =
                    make_int4(CONTENT_PAD, CONTENT_PAD, CONTENT_PAD, CONTENT_PAD);
                *reinterpret_cast<int4*>(dst_p + s0) =
                    make_int4(ppad, ppad, ppad, ppad);
            } else {
                // boundary chunk (contains EOS): full predicate path
                int4 vc4, vp4;
                elem(s0 + 0, vc4.x, vp4.x);
                elem(s0 + 1, vc4.y, vp4.y);
                elem(s0 + 2, vc4.z, vp4.z);
                elem(s0 + 3, vc4.w, vp4.w);
                *reinterpret_cast<int4*>(dst_c + s0) = vc4;
                *reinterpret_cast<int4*>(dst_p + s0) = vp4;
            }
        }
        if (t < rem) {                       // tail scalars
            const int slot = M_OUT - rem + t;
            int vc, vp;
            elem(slot, vc, vp);
            dst_c[slot] = vc; dst_p[slot] = vp;
        }
    }
}

extern "C" void kernel_launch(void* const* d_in, const int* in_sizes, int n_in,
                              void* d_out, int out_size, void* d_ws, size_t ws_size,
                              hipStream_t stream) {
    const int* indices = (const int*)d_in[0];
    const int* grain   = (const int*)d_in[1];
    int* out = (int*)d_out;

    const int batch = in_sizes[0] / N_TOK;  // 512
    triple_grain_permute<<<batch, TPB, 0, stream>>>(indices, grain, out, batch);
}